// Round 9
// baseline (260.340 us; speedup 1.0000x reference)
//
#include <hip/hip_runtime.h>
#include <hip/hip_fp16.h>

#define N_NODES 50000
#define N_EDGES 800000
#define D 64
#define NUM_GRAPHS 512
#define FINAL_NEURON 128
#define SCAN_NB ((N_NODES + 255) / 256)   // 196

#define BN 16                              // nodes per GEMM tile (50000/16 exact)
#define NB_GEMM (N_NODES / BN)             // 3125
#define NB_EDGE (N_EDGES / 256)            // 3125 exact
#define BKT 64                             // CSR bucket capacity per node
#define ZS 72                              // LDS stride (halves)
#define WS 72
#define WELEM (D * WS)                     // 4608 halves per prepared W image

typedef unsigned short ushort_t;
typedef _Float16 f16;
typedef __attribute__((ext_vector_type(4))) _Float16 f16x4;
typedef __attribute__((ext_vector_type(8))) _Float16 f16x8;
typedef __attribute__((ext_vector_type(4))) float f32x4;

struct WPtrs { const float* w[5]; };

__device__ __forceinline__ float2 h2f(unsigned v) {
    __half2 h = *reinterpret_cast<__half2*>(&v);
    return __half22float2(h);
}

__device__ __forceinline__ void acc_add8(float4& a0, float4& a1, uint4 u) {
    float2 p;
    p = h2f(u.x); a0.x += p.x; a0.y += p.y;
    p = h2f(u.y); a0.z += p.x; a0.w += p.y;
    p = h2f(u.z); a1.x += p.x; a1.y += p.y;
    p = h2f(u.w); a1.z += p.x; a1.w += p.y;
}

// ---------------- preamble: zero + W hi/lo prep ----------------
__global__ void k_zero_prep(int* cnt, float* g,
                            WPtrs wp, f16* __restrict__ whi, f16* __restrict__ wlo) {
    int b = blockIdx.x;
    if (b < SCAN_NB) {
        int i = b * 256 + threadIdx.x;
        if (i < N_NODES) cnt[i] = 0;
        if (i < NUM_GRAPHS * D) g[i] = 0.f;
        return;
    }
    int l = b - SCAN_NB;                 // 0..4
    const float* W = wp.w[l];
    f16* hi = whi + l * WELEM;
    f16* lo = wlo + l * WELEM;
    for (int idx = threadIdx.x; idx < D * D; idx += 256) {
        int k = idx >> 6, j = idx & 63;
        float w = W[idx];
        f16 h = (f16)w;
        hi[j * WS + k] = h;
        lo[j * WS + k] = (f16)(w - (float)h);
    }
}

// hist: returning atomic + COALESCED epos write (no random scatter here —
// R8's atomic->random-2B-scatter chain write-amplified 44MB / 52us).
__global__ void k_hist(const int* __restrict__ dst, int* cnt,
                       ushort_t* __restrict__ epos) {
    int e = blockIdx.x * 256 + threadIdx.x;
    epos[e] = (ushort_t)atomicAdd(&cnt[dst[e]], 1);
}

// dinv + capped degree + per-256-block bitonic sort by degree -> perm.
// No global atomics (R7's 65-counter storm was 108 us).
__global__ void k_dsort(const int* __restrict__ cnt, float* __restrict__ dinv,
                        int* __restrict__ degc, int* __restrict__ perm) {
    __shared__ int skey[256], sval[256];
    int t = threadIdx.x;
    int i = blockIdx.x * 256 + t;
    int kk = -1;
    if (i < N_NODES) {
        int c = cnt[i];
        dinv[i] = rsqrtf((float)c + 1.0f);
        int cc = c < BKT ? c : BKT;
        degc[i] = cc;
        kk = cc;                          // pads keep -1 -> sort last
    }
    skey[t] = kk;
    sval[t] = i;
    __syncthreads();
    // bitonic sort, descending by key (pads land at block end)
    for (int k = 2; k <= 256; k <<= 1) {
        for (int j = k >> 1; j > 0; j >>= 1) {
            int ixj = t ^ j;
            if (ixj > t) {
                int ka = skey[t], kb = skey[ixj];
                bool asc = ((t & k) == 0);
                bool sw = asc ? (ka < kb) : (ka > kb);
                if (sw) {
                    skey[t] = kb; skey[ixj] = ka;
                    int va = sval[t]; sval[t] = sval[ixj]; sval[ixj] = va;
                }
            }
            __syncthreads();
        }
    }
    if (i < N_NODES) perm[i] = sval[t];   // first (valid) slots hold real nodes
}

// ---------------- gather: contiguous-half split, 8-wide rounds (verified) ----
struct GS { int e, m; int i0, i1, i2, i3, i4, i5, i6, i7; };

__device__ __forceinline__ void gh_prologue(const int* __restrict__ deg,
                                            const ushort_t* __restrict__ esrc,
                                            int n, int g, GS& S) {
    int d = deg[n];
    int h0 = (d + 1) >> 1;
    int e = (n << 6) + (g ? h0 : 0);
    S.e = e; S.m = g ? (d - h0) : h0;
    S.i0 = esrc[e];     S.i1 = esrc[e + 1]; S.i2 = esrc[e + 2]; S.i3 = esrc[e + 3];
    S.i4 = esrc[e + 4]; S.i5 = esrc[e + 5]; S.i6 = esrc[e + 6]; S.i7 = esrc[e + 7];
}

__device__ __forceinline__ void gh_rounds(const ushort_t* __restrict__ esrc,
                                          const uint4* __restrict__ hp,
                                          int n, int g, int q, GS S,
                                          float4& a0, float4& a1) {
    if (g) acc_add8(a0, a1, hp[(size_t)n * 8 + q]);   // self-loop (shorter half)
    int e = S.e, m = S.m;
    int i0 = S.i0, i1 = S.i1, i2 = S.i2, i3 = S.i3;
    int i4 = S.i4, i5 = S.i5, i6 = S.i6, i7 = S.i7;
    if (m >= 8) {
        for (;;) {
            uint4 u0 = hp[(size_t)i0 * 8 + q], u1 = hp[(size_t)i1 * 8 + q];
            uint4 u2 = hp[(size_t)i2 * 8 + q], u3 = hp[(size_t)i3 * 8 + q];
            uint4 u4 = hp[(size_t)i4 * 8 + q], u5 = hp[(size_t)i5 * 8 + q];
            uint4 u6 = hp[(size_t)i6 * 8 + q], u7 = hp[(size_t)i7 * 8 + q];
            e += 8; m -= 8;
            i0 = esrc[e];     i1 = esrc[e + 1]; i2 = esrc[e + 2]; i3 = esrc[e + 3];
            i4 = esrc[e + 4]; i5 = esrc[e + 5]; i6 = esrc[e + 6]; i7 = esrc[e + 7];
            acc_add8(a0, a1, u0); acc_add8(a0, a1, u1);
            acc_add8(a0, a1, u2); acc_add8(a0, a1, u3);
            acc_add8(a0, a1, u4); acc_add8(a0, a1, u5);
            acc_add8(a0, a1, u6); acc_add8(a0, a1, u7);
            if (m < 8) break;
        }
    }
    if (m <= 0) return;
    if (m & 4) {
        uint4 u0 = hp[(size_t)i0 * 8 + q], u1 = hp[(size_t)i1 * 8 + q];
        uint4 u2 = hp[(size_t)i2 * 8 + q], u3 = hp[(size_t)i3 * 8 + q];
        acc_add8(a0, a1, u0); acc_add8(a0, a1, u1);
        acc_add8(a0, a1, u2); acc_add8(a0, a1, u3);
        i0 = i4; i1 = i5; i2 = i6; i3 = i7;
    }
    if (m & 2) {
        uint4 u0 = hp[(size_t)i0 * 8 + q], u1 = hp[(size_t)i1 * 8 + q];
        acc_add8(a0, a1, u0); acc_add8(a0, a1, u1);
        i0 = i2; i1 = i3;
    }
    if (m & 1) {
        uint4 u0 = hp[(size_t)i0 * 8 + q];
        acc_add8(a0, a1, u0);
    }
}

// ---------------- 16x64 @ 64x64 MFMA GEMM, W from global (verified) ----------
__device__ __forceinline__ void gemm_16x64_reg(f16* zsh,
                                               const f16* __restrict__ whi_g,
                                               const f16* __restrict__ wlo_g,
                                               const float* dinvsh, int t) {
    int w = t >> 6, l = t & 63;
    int cb = w * 16;
    int lr = l & 15, lg = l >> 4;
    const f16* bhp = &whi_g[(cb + lr) * WS + lg * 8];
    const f16* blp = &wlo_g[(cb + lr) * WS + lg * 8];
    f16x8 bh0 = *(const f16x8*)bhp;
    f16x8 bl0 = *(const f16x8*)blp;
    f16x8 bh1 = *(const f16x8*)(bhp + 32);
    f16x8 bl1 = *(const f16x8*)(blp + 32);
    f32x4 acc = {0.f, 0.f, 0.f, 0.f};
    f16x8 a0 = *(const f16x8*)&zsh[lr * ZS + lg * 8];
    f16x8 a1 = *(const f16x8*)&zsh[lr * ZS + 32 + lg * 8];
    acc = __builtin_amdgcn_mfma_f32_16x16x32_f16(a0, bh0, acc, 0, 0, 0);
    acc = __builtin_amdgcn_mfma_f32_16x16x32_f16(a0, bl0, acc, 0, 0, 0);
    acc = __builtin_amdgcn_mfma_f32_16x16x32_f16(a1, bh1, acc, 0, 0, 0);
    acc = __builtin_amdgcn_mfma_f32_16x16x32_f16(a1, bl1, acc, 0, 0, 0);
    __syncthreads();                 // all zsh reads done before overwrite
    // C/D layout: col = lane&15, row = (lane>>4)*4 + reg
#pragma unroll
    for (int r = 0; r < 4; ++r) {
        int rrow = lg * 4 + r;
        float s = dinvsh[rrow];
        zsh[rrow * ZS + cb + lr] = (f16)(acc[r] * s);
    }
}

// ---------------- transform0: y1 = dinv .* (x @ W1); + esrc bucket fill ------
// Fill range has NO atomics: two parallel loads (dst, epos) + scatter write,
// latency hidden under the co-resident GEMM blocks (R5's proven pattern).
__global__ __launch_bounds__(256, 8)
void k_transform0(const float* __restrict__ x, const float* __restrict__ dinv,
                  const f16* __restrict__ whi_g, const f16* __restrict__ wlo_g,
                  __half* __restrict__ hout,
                  const int* __restrict__ src, const int* __restrict__ dst,
                  const ushort_t* __restrict__ epos, ushort_t* __restrict__ esrc) {
    int t = threadIdx.x;
    if (blockIdx.x >= NB_GEMM) {           // fill blocks
        int e = (blockIdx.x - NB_GEMM) * 256 + t;
        int d = dst[e];
        int p = epos[e];
        if (p < BKT)
            __builtin_nontemporal_store((ushort_t)src[e], esrc + d * BKT + p);
        return;
    }
    __shared__ __attribute__((aligned(16))) f16 zsh[BN * ZS];
    __shared__ float dinvsh[BN];
    int base = blockIdx.x * BN;
    if (t < BN) dinvsh[t] = dinv[base + t];

    int nl = t >> 4, c4 = t & 15;
    float4 xv = ((const float4*)x)[(size_t)(base + nl) * 16 + c4];
    f16x4 zv = {(f16)xv.x, (f16)xv.y, (f16)xv.z, (f16)xv.w};
    *(f16x4*)&zsh[nl * ZS + c4 * 4] = zv;
    __syncthreads();
    gemm_16x64_reg(zsh, whi_g, wlo_g, dinvsh, t);
    __syncthreads();
    if (t < 128) {
        int n2 = t >> 3, q = t & 7;
        uint4 o = *(const uint4*)&zsh[n2 * ZS + q * 8];
        ((uint4*)hout)[(size_t)(base + n2) * 8 + q] = o;
    }
}

// ---------------- fused layer: degree-sorted tiles (perm), bucket CSR --------
__global__ __launch_bounds__(256, 7)
void k_layer(const int* __restrict__ degc, const ushort_t* __restrict__ esrc,
             const int* __restrict__ perm,
             const __half* __restrict__ hin, const float* __restrict__ dinv,
             const float* __restrict__ bias,
             const f16* __restrict__ whi_g, const f16* __restrict__ wlo_g,
             __half* __restrict__ hout) {
    __shared__ __attribute__((aligned(16))) f16 zsh[BN * ZS];
    __shared__ float dinvsh[BN];
    int t = threadIdx.x;
    int base = blockIdx.x * BN;
    if (t < BN) dinvsh[t] = dinv[perm[base + t]];

    int nl = t >> 4, m16 = t & 15, g = m16 >> 3, q = m16 & 7;
    int n = perm[base + nl];               // wave's 4 nodes have ~equal degree
    GS S;
    gh_prologue(degc, esrc, n, g, S);
    float4 a0, a1;
    a0.x = a0.y = a0.z = a0.w = 0.f;
    a1.x = a1.y = a1.z = a1.w = 0.f;
    gh_rounds(esrc, (const uint4*)hin, n, g, q, S, a0, a1);
    a0.x += __shfl_xor(a0.x, 8); a0.y += __shfl_xor(a0.y, 8);
    a0.z += __shfl_xor(a0.z, 8); a0.w += __shfl_xor(a0.w, 8);
    a1.x += __shfl_xor(a1.x, 8); a1.y += __shfl_xor(a1.y, 8);
    a1.z += __shfl_xor(a1.z, 8); a1.w += __shfl_xor(a1.w, 8);
    float s = dinv[n];
    float4 b0 = ((const float4*)bias)[2 * q];
    float4 b1 = ((const float4*)bias)[2 * q + 1];
    if (g == 0) {
        f16x8 zv;
        zv[0] = (f16)fmaxf(a0.x * s + b0.x, 0.f);
        zv[1] = (f16)fmaxf(a0.y * s + b0.y, 0.f);
        zv[2] = (f16)fmaxf(a0.z * s + b0.z, 0.f);
        zv[3] = (f16)fmaxf(a0.w * s + b0.w, 0.f);
        zv[4] = (f16)fmaxf(a1.x * s + b1.x, 0.f);
        zv[5] = (f16)fmaxf(a1.y * s + b1.y, 0.f);
        zv[6] = (f16)fmaxf(a1.z * s + b1.z, 0.f);
        zv[7] = (f16)fmaxf(a1.w * s + b1.w, 0.f);
        *(f16x8*)&zsh[nl * ZS + q * 8] = zv;
    }
    __syncthreads();
    gemm_16x64_reg(zsh, whi_g, wlo_g, dinvsh, t);
    __syncthreads();
    if (t < 128) {
        int n2 = t >> 3, q2 = t & 7;
        int prow = perm[base + n2];
        uint4 o = *(const uint4*)&zsh[n2 * ZS + q2 * 8];
        ((uint4*)hout)[(size_t)prow * 8 + q2] = o;
    }
}

// ---------------- final layer: gather + relu/bias + fused pool (natural) -----
__global__ __launch_bounds__(256, 7)
void k_layer_pool(const int* __restrict__ degc, const ushort_t* __restrict__ esrc,
                  const __half* __restrict__ hin, const float* __restrict__ dinv,
                  const float* __restrict__ bias, const int* __restrict__ batch,
                  float* __restrict__ g) {
    __shared__ float zf[BN * 68];
    __shared__ int bsh[BN];
    int t = threadIdx.x;
    int base = blockIdx.x * BN;
    if (t < BN) bsh[t] = batch[base + t];

    int nl = t >> 4, m = t & 15, g2 = m >> 3, q = m & 7;
    int n = base + nl;
    GS S;
    gh_prologue(degc, esrc, n, g2, S);
    float4 a0, a1;
    a0.x = a0.y = a0.z = a0.w = 0.f;
    a1.x = a1.y = a1.z = a1.w = 0.f;
    gh_rounds(esrc, (const uint4*)hin, n, g2, q, S, a0, a1);
    a0.x += __shfl_xor(a0.x, 8); a0.y += __shfl_xor(a0.y, 8);
    a0.z += __shfl_xor(a0.z, 8); a0.w += __shfl_xor(a0.w, 8);
    a1.x += __shfl_xor(a1.x, 8); a1.y += __shfl_xor(a1.y, 8);
    a1.z += __shfl_xor(a1.z, 8); a1.w += __shfl_xor(a1.w, 8);
    float s = dinv[n];
    float4 b0 = ((const float4*)bias)[2 * q];
    float4 b1 = ((const float4*)bias)[2 * q + 1];
    if (g2 == 0) {
        float4 r0, r1;
        r0.x = fmaxf(a0.x * s + b0.x, 0.f);
        r0.y = fmaxf(a0.y * s + b0.y, 0.f);
        r0.z = fmaxf(a0.z * s + b0.z, 0.f);
        r0.w = fmaxf(a0.w * s + b0.w, 0.f);
        r1.x = fmaxf(a1.x * s + b1.x, 0.f);
        r1.y = fmaxf(a1.y * s + b1.y, 0.f);
        r1.z = fmaxf(a1.z * s + b1.z, 0.f);
        r1.w = fmaxf(a1.w * s + b1.w, 0.f);
        *(float4*)&zf[nl * 68 + q * 8]     = r0;
        *(float4*)&zf[nl * 68 + q * 8 + 4] = r1;
    }
    __syncthreads();
    // pool: 4 groups x 4 nodes, 64 feats; batch sorted -> few boundary atomics
    int f = t & 63, grp = t >> 6;
    int n0 = grp * 4;
    int cur = bsh[n0];
    float acc = 0.f;
#pragma unroll
    for (int k2 = 0; k2 < 4; ++k2) {
        int bb = bsh[n0 + k2];
        if (bb != cur) { atomicAdd(&g[cur * D + f], acc); acc = 0.f; cur = bb; }
        acc += zf[(n0 + k2) * 68 + f];
    }
    atomicAdd(&g[cur * D + f], acc);
}

// ---------------- fused MLP ----------------
__global__ void k_mlp(const float* __restrict__ g, const float* __restrict__ W1,
                      const float* __restrict__ b1, const float* __restrict__ W2,
                      const float* __restrict__ b2, float* __restrict__ out) {
    __shared__ float red[FINAL_NEURON];
    int row = blockIdx.x;
    int j = threadIdx.x;
    float acc = 0.f;
#pragma unroll
    for (int k = 0; k < D; ++k) acc += g[row * D + k] * W1[k * FINAL_NEURON + j];
    acc = fmaxf(acc + b1[j], 0.f);
    red[j] = acc * W2[j];
    __syncthreads();
    for (int s = 64; s > 0; s >>= 1) {
        if (j < s) red[j] += red[j + s];
        __syncthreads();
    }
    if (j == 0) out[row] = red[0] + b2[0];
}

extern "C" void kernel_launch(void* const* d_in, const int* in_sizes, int n_in,
                              void* d_out, int out_size, void* d_ws, size_t ws_size,
                              hipStream_t stream) {
    const float* x     = (const float*)d_in[0];
    const int*   ei    = (const int*)d_in[1];
    const int*   src   = ei;
    const int*   dst   = ei + N_EDGES;
    const int*   batch = (const int*)d_in[2];
    WPtrs wp;
    wp.w[0] = (const float*)d_in[3];  wp.w[1] = (const float*)d_in[5];
    wp.w[2] = (const float*)d_in[7];  wp.w[3] = (const float*)d_in[9];
    wp.w[4] = (const float*)d_in[11];
    const float* b[5]  = {(const float*)d_in[4], (const float*)d_in[6], (const float*)d_in[8],
                          (const float*)d_in[10], (const float*)d_in[12]};
    const float* fc1W  = (const float*)d_in[13];
    const float* fc1b  = (const float*)d_in[14];
    const float* fc2W  = (const float*)d_in[15];
    const float* fc2b  = (const float*)d_in[16];
    float* out = (float*)d_out;

    __half*   yA      = (__half*)d_ws;                       // [N][64] fp16
    __half*   yB      = yA + (size_t)N_NODES * D;            // [N][64] fp16
    f16*      whiG    = (f16*)(yB + (size_t)N_NODES * D);    // 5 * WELEM
    f16*      wloG    = whiG + 5 * WELEM;                    // 5 * WELEM
    float*    g       = (float*)(wloG + 5 * WELEM);          // G*D
    float*    dinv    = g + NUM_GRAPHS * D;                  // N
    int*      cnt     = (int*)(dinv + N_NODES);              // N
    int*      degc    = cnt + N_NODES;                       // N
    int*      perm    = degc + N_NODES;                      // N
    ushort_t* epos    = (ushort_t*)(perm + N_NODES);         // E
    ushort_t* esrc    = epos + N_EDGES;                      // N*BKT + pad

    // ---- preamble: zero + W prep | hist (atomic, coalesced epos) | sort ----
    k_zero_prep<<<SCAN_NB + 5, 256, 0, stream>>>(cnt, g, wp, whiG, wloG);
    k_hist<<<NB_EDGE, 256, 0, stream>>>(dst, cnt, epos);
    k_dsort<<<SCAN_NB, 256, 0, stream>>>(cnt, dinv, degc, perm);

    // ---- y1 = dinv*(x@W1) + esrc bucket fill (no atomics, overlapped) ----
    k_transform0<<<NB_GEMM + NB_EDGE, 256, 0, stream>>>(x, dinv, whiG, wloG, yA,
                                                        src, dst, epos, esrc);

    // ---- 4 fused GCN layers (block-locally degree-sorted tiles) ----
    k_layer<<<NB_GEMM, 256, 0, stream>>>(degc, esrc, perm, yA, dinv, b[0],
                                         whiG + 1 * WELEM, wloG + 1 * WELEM, yB);
    k_layer<<<NB_GEMM, 256, 0, stream>>>(degc, esrc, perm, yB, dinv, b[1],
                                         whiG + 2 * WELEM, wloG + 2 * WELEM, yA);
    k_layer<<<NB_GEMM, 256, 0, stream>>>(degc, esrc, perm, yA, dinv, b[2],
                                         whiG + 3 * WELEM, wloG + 3 * WELEM, yB);
    k_layer<<<NB_GEMM, 256, 0, stream>>>(degc, esrc, perm, yB, dinv, b[3],
                                         whiG + 4 * WELEM, wloG + 4 * WELEM, yA);

    // ---- layer 5 + fused global_add_pool (natural order) ----
    k_layer_pool<<<NB_GEMM, 256, 0, stream>>>(degc, esrc, yA, dinv, b[4], batch, g);

    // ---- MLP ----
    k_mlp<<<NUM_GRAPHS, FINAL_NEURON, 0, stream>>>(g, fc1W, fc1b, fc2W, fc2b, out);
}

// Round 10
// 259.536 us; speedup vs baseline: 1.0031x; 1.0031x over previous
//
#include <hip/hip_runtime.h>
#include <hip/hip_fp16.h>

#define N_NODES 50000
#define N_EDGES 800000
#define D 64
#define NUM_GRAPHS 512
#define FINAL_NEURON 128
#define SCAN_NB ((N_NODES + 255) / 256)   // 196

#define BN 16                              // nodes per GEMM tile (50000/16 exact)
#define NB_GEMM (N_NODES / BN)             // 3125
#define NB_EDGE (N_EDGES / 256)            // 3125 exact
#define ZS 72                              // LDS stride (halves)
#define WS 72
#define WELEM (D * WS)                     // 4608 halves per prepared W image

typedef unsigned short ushort_t;
typedef _Float16 f16;
typedef __attribute__((ext_vector_type(4))) _Float16 f16x4;
typedef __attribute__((ext_vector_type(8))) _Float16 f16x8;
typedef __attribute__((ext_vector_type(4))) float f32x4;

struct WPtrs { const float* w[5]; };

__device__ __forceinline__ float2 h2f(unsigned v) {
    __half2 h = *reinterpret_cast<__half2*>(&v);
    return __half22float2(h);
}

__device__ __forceinline__ void acc_add8(float4& a0, float4& a1, uint4 u) {
    float2 p;
    p = h2f(u.x); a0.x += p.x; a0.y += p.y;
    p = h2f(u.y); a0.z += p.x; a0.w += p.y;
    p = h2f(u.z); a1.x += p.x; a1.y += p.y;
    p = h2f(u.w); a1.z += p.x; a1.w += p.y;
}

// ---------------- CSR build + W hi/lo prep (R5-verified) ----------------
__global__ void k_zero_prep(int* cnt, WPtrs wp, f16* __restrict__ whi, f16* __restrict__ wlo) {
    int b = blockIdx.x;
    if (b < SCAN_NB) {
        int i = b * 256 + threadIdx.x;
        if (i < N_NODES) cnt[i] = 0;
        return;
    }
    int l = b - SCAN_NB;                 // 0..4
    const float* W = wp.w[l];
    f16* hi = whi + l * WELEM;
    f16* lo = wlo + l * WELEM;
    for (int idx = threadIdx.x; idx < D * D; idx += 256) {
        int k = idx >> 6, j = idx & 63;
        float w = W[idx];
        f16 h = (f16)w;
        hi[j * WS + k] = h;
        lo[j * WS + k] = (f16)(w - (float)h);
    }
}

// hist: returning atomic + coalesced epos write (packed row-CSR rank)
__global__ void k_hist(const int* __restrict__ dst, int* cnt, ushort_t* __restrict__ epos) {
    int e = blockIdx.x * 256 + threadIdx.x;
    epos[e] = (ushort_t)atomicAdd(&cnt[dst[e]], 1);
}

__global__ void k_blocksum(const int* __restrict__ cnt, int* __restrict__ bsum,
                           float* __restrict__ dinv, float* __restrict__ g) {
    __shared__ int sdata[256];
    int t = threadIdx.x;
    int i = blockIdx.x * 256 + t;
    int v = (i < N_NODES) ? cnt[i] : 0;
    if (i < N_NODES) dinv[i] = rsqrtf((float)v + 1.0f);
    if (i < NUM_GRAPHS * D) g[i] = 0.f;
    sdata[t] = v;
    __syncthreads();
    for (int s = 128; s > 0; s >>= 1) {
        if (t < s) sdata[t] += sdata[t + s];
        __syncthreads();
    }
    if (t == 0) bsum[blockIdx.x] = sdata[0];
}

// merged scan: each block derives its own exclusive offset from bsum in LDS
// (redundant 256-wide scan, trivially parallel) then local-scans its cnt chunk.
// Eliminates the 1-block k_scanbsum serialization point.
__global__ void k_localscan(const int* __restrict__ bsum, const int* __restrict__ cnt,
                            int* __restrict__ row) {
    __shared__ int buf[256];
    int t = threadIdx.x;
    // pass 1: inclusive scan over the 196 block sums
    int bv = (t < SCAN_NB) ? bsum[t] : 0;
    buf[t] = bv;
    __syncthreads();
    for (int off = 1; off < 256; off <<= 1) {
        int a = (t >= off) ? buf[t - off] : 0;
        __syncthreads();
        buf[t] += a;
        __syncthreads();
    }
    int boff = buf[blockIdx.x] - bsum[blockIdx.x];   // exclusive prefix (uniform)
    __syncthreads();
    // pass 2: local scan of this block's cnt chunk
    int i = blockIdx.x * 256 + t;
    int v = (i < N_NODES) ? cnt[i] : 0;
    buf[t] = v;
    __syncthreads();
    for (int off = 1; off < 256; off <<= 1) {
        int a = (t >= off) ? buf[t - off] : 0;
        __syncthreads();
        buf[t] += a;
        __syncthreads();
    }
    if (i < N_NODES) row[i] = boff + buf[t] - v;
    if (i == 0) row[N_NODES] = N_EDGES;
}

// ---------------- gather: contiguous-half split, 8-wide rounds (verified) ----
__device__ __forceinline__ void gather_half(const int* __restrict__ row,
                                            const ushort_t* __restrict__ esrc,
                                            const uint4* __restrict__ hp,
                                            int n, int g, int q,
                                            float4& a0, float4& a1) {
    int e0 = row[n], e1 = row[n + 1];
    int len = e1 - e0;
    int h0 = (len + 1) >> 1;
    int e  = g ? (e0 + h0) : e0;
    int eg = g ? e1 : (e0 + h0);
    if (g) acc_add8(a0, a1, hp[(size_t)n * 8 + q]);   // self-loop (shorter half)
    int m = eg - e;
    int i0, i1, i2, i3, i4, i5, i6, i7;
    if (m >= 8) {
        i0 = esrc[e];     i1 = esrc[e + 1]; i2 = esrc[e + 2]; i3 = esrc[e + 3];
        i4 = esrc[e + 4]; i5 = esrc[e + 5]; i6 = esrc[e + 6]; i7 = esrc[e + 7];
        for (;;) {
            uint4 u0 = hp[(size_t)i0 * 8 + q], u1 = hp[(size_t)i1 * 8 + q];
            uint4 u2 = hp[(size_t)i2 * 8 + q], u3 = hp[(size_t)i3 * 8 + q];
            uint4 u4 = hp[(size_t)i4 * 8 + q], u5 = hp[(size_t)i5 * 8 + q];
            uint4 u6 = hp[(size_t)i6 * 8 + q], u7 = hp[(size_t)i7 * 8 + q];
            e += 8; m -= 8;
            i0 = esrc[e];     i1 = esrc[e + 1]; i2 = esrc[e + 2]; i3 = esrc[e + 3];
            i4 = esrc[e + 4]; i5 = esrc[e + 5]; i6 = esrc[e + 6]; i7 = esrc[e + 7];
            acc_add8(a0, a1, u0); acc_add8(a0, a1, u1);
            acc_add8(a0, a1, u2); acc_add8(a0, a1, u3);
            acc_add8(a0, a1, u4); acc_add8(a0, a1, u5);
            acc_add8(a0, a1, u6); acc_add8(a0, a1, u7);
            if (m < 8) break;
        }
        // i0..i7 hold the next 8 prefetched entries; first m are valid tail
    } else {
        if (m <= 0) return;
        i0 = esrc[e];     i1 = esrc[e + 1]; i2 = esrc[e + 2]; i3 = esrc[e + 3];
        i4 = esrc[e + 4]; i5 = esrc[e + 5]; i6 = esrc[e + 6]; i7 = esrc[e + 7];
    }
    if (m & 4) {
        uint4 u0 = hp[(size_t)i0 * 8 + q], u1 = hp[(size_t)i1 * 8 + q];
        uint4 u2 = hp[(size_t)i2 * 8 + q], u3 = hp[(size_t)i3 * 8 + q];
        acc_add8(a0, a1, u0); acc_add8(a0, a1, u1);
        acc_add8(a0, a1, u2); acc_add8(a0, a1, u3);
        i0 = i4; i1 = i5; i2 = i6; i3 = i7;
    }
    if (m & 2) {
        uint4 u0 = hp[(size_t)i0 * 8 + q], u1 = hp[(size_t)i1 * 8 + q];
        acc_add8(a0, a1, u0); acc_add8(a0, a1, u1);
        i0 = i2; i1 = i3;
    }
    if (m & 1) {
        uint4 u0 = hp[(size_t)i0 * 8 + q];
        acc_add8(a0, a1, u0);
    }
}

// ---------------- 16x64 @ 64x64 MFMA GEMM, W from global (verified) ----------
__device__ __forceinline__ void gemm_16x64_reg(f16* zsh,
                                               const f16* __restrict__ whi_g,
                                               const f16* __restrict__ wlo_g,
                                               const float* dinvsh, int t) {
    int w = t >> 6, l = t & 63;
    int cb = w * 16;
    int lr = l & 15, lg = l >> 4;
    const f16* bhp = &whi_g[(cb + lr) * WS + lg * 8];
    const f16* blp = &wlo_g[(cb + lr) * WS + lg * 8];
    f16x8 bh0 = *(const f16x8*)bhp;
    f16x8 bl0 = *(const f16x8*)blp;
    f16x8 bh1 = *(const f16x8*)(bhp + 32);
    f16x8 bl1 = *(const f16x8*)(blp + 32);
    f32x4 acc = {0.f, 0.f, 0.f, 0.f};
    f16x8 a0 = *(const f16x8*)&zsh[lr * ZS + lg * 8];
    f16x8 a1 = *(const f16x8*)&zsh[lr * ZS + 32 + lg * 8];
    acc = __builtin_amdgcn_mfma_f32_16x16x32_f16(a0, bh0, acc, 0, 0, 0);
    acc = __builtin_amdgcn_mfma_f32_16x16x32_f16(a0, bl0, acc, 0, 0, 0);
    acc = __builtin_amdgcn_mfma_f32_16x16x32_f16(a1, bh1, acc, 0, 0, 0);
    acc = __builtin_amdgcn_mfma_f32_16x16x32_f16(a1, bl1, acc, 0, 0, 0);
    __syncthreads();                 // all zsh reads done before overwrite
    // C/D layout: col = lane&15, row = (lane>>4)*4 + reg
#pragma unroll
    for (int r = 0; r < 4; ++r) {
        int rrow = lg * 4 + r;
        float s = dinvsh[rrow];
        zsh[rrow * ZS + cb + lr] = (f16)(acc[r] * s);
    }
}

// ---------------- transform0: y1 = dinv .* (x @ W1), fp16; + CSR edge fill ---
__global__ __launch_bounds__(256, 8)
void k_transform0(const float* __restrict__ x, const float* __restrict__ dinv,
                  const f16* __restrict__ whi_g, const f16* __restrict__ wlo_g,
                  __half* __restrict__ hout,
                  const int* __restrict__ src, const int* __restrict__ dst,
                  const int* __restrict__ row, const ushort_t* __restrict__ epos,
                  ushort_t* __restrict__ esrc) {
    int t = threadIdx.x;
    if (blockIdx.x >= NB_GEMM) {           // fill blocks (packed row-CSR scatter)
        int e = (blockIdx.x - NB_GEMM) * 256 + t;
        __builtin_nontemporal_store((ushort_t)src[e], esrc + row[dst[e]] + (int)epos[e]);
        return;
    }
    __shared__ __attribute__((aligned(16))) f16 zsh[BN * ZS];
    __shared__ float dinvsh[BN];
    int base = blockIdx.x * BN;
    if (t < BN) dinvsh[t] = dinv[base + t];

    int nl = t >> 4, c4 = t & 15;
    float4 xv = ((const float4*)x)[(size_t)(base + nl) * 16 + c4];
    f16x4 zv = {(f16)xv.x, (f16)xv.y, (f16)xv.z, (f16)xv.w};
    *(f16x4*)&zsh[nl * ZS + c4 * 4] = zv;
    __syncthreads();
    gemm_16x64_reg(zsh, whi_g, wlo_g, dinvsh, t);
    __syncthreads();
    if (t < 128) {
        int n2 = t >> 3, q = t & 7;
        uint4 o = *(const uint4*)&zsh[n2 * ZS + q * 8];
        ((uint4*)hout)[(size_t)(base + n2) * 8 + q] = o;
    }
}

// ---------------- fused layer: gather + relu/bias + (z @ Wnext)*dinv ---------
__global__ __launch_bounds__(256, 7)
void k_layer(const int* __restrict__ row, const ushort_t* __restrict__ esrc,
             const __half* __restrict__ hin, const float* __restrict__ dinv,
             const float* __restrict__ bias,
             const f16* __restrict__ whi_g, const f16* __restrict__ wlo_g,
             __half* __restrict__ hout) {
    __shared__ __attribute__((aligned(16))) f16 zsh[BN * ZS];
    __shared__ float dinvsh[BN];
    int t = threadIdx.x;
    int base = blockIdx.x * BN;
    if (t < BN) dinvsh[t] = dinv[base + t];

    int nl = t >> 4, m = t & 15, g = m >> 3, q = m & 7;
    int n = base + nl;
    float4 a0 = {0,0,0,0}, a1 = {0,0,0,0};
    gather_half(row, esrc, (const uint4*)hin, n, g, q, a0, a1);
    // merge the two edge-half partials
    a0.x += __shfl_xor(a0.x, 8); a0.y += __shfl_xor(a0.y, 8);
    a0.z += __shfl_xor(a0.z, 8); a0.w += __shfl_xor(a0.w, 8);
    a1.x += __shfl_xor(a1.x, 8); a1.y += __shfl_xor(a1.y, 8);
    a1.z += __shfl_xor(a1.z, 8); a1.w += __shfl_xor(a1.w, 8);
    float s = dinv[n];
    float4 b0 = ((const float4*)bias)[2 * q];
    float4 b1 = ((const float4*)bias)[2 * q + 1];
    if (g == 0) {
        f16x8 zv;
        zv[0] = (f16)fmaxf(a0.x * s + b0.x, 0.f);
        zv[1] = (f16)fmaxf(a0.y * s + b0.y, 0.f);
        zv[2] = (f16)fmaxf(a0.z * s + b0.z, 0.f);
        zv[3] = (f16)fmaxf(a0.w * s + b0.w, 0.f);
        zv[4] = (f16)fmaxf(a1.x * s + b1.x, 0.f);
        zv[5] = (f16)fmaxf(a1.y * s + b1.y, 0.f);
        zv[6] = (f16)fmaxf(a1.z * s + b1.z, 0.f);
        zv[7] = (f16)fmaxf(a1.w * s + b1.w, 0.f);
        *(f16x8*)&zsh[nl * ZS + q * 8] = zv;
    }
    __syncthreads();
    gemm_16x64_reg(zsh, whi_g, wlo_g, dinvsh, t);
    __syncthreads();
    if (t < 128) {
        int n2 = t >> 3, q2 = t & 7;
        uint4 o = *(const uint4*)&zsh[n2 * ZS + q2 * 8];
        ((uint4*)hout)[(size_t)(base + n2) * 8 + q2] = o;
    }
}

// ---------------- final layer: gather + relu/bias + fused global_add_pool ----
__global__ __launch_bounds__(256, 7)
void k_layer_pool(const int* __restrict__ row, const ushort_t* __restrict__ esrc,
                  const __half* __restrict__ hin, const float* __restrict__ dinv,
                  const float* __restrict__ bias, const int* __restrict__ batch,
                  float* __restrict__ g) {
    __shared__ float zf[BN * 68];
    __shared__ int bsh[BN];
    int t = threadIdx.x;
    int base = blockIdx.x * BN;
    if (t < BN) bsh[t] = batch[base + t];

    int nl = t >> 4, m = t & 15, g2 = m >> 3, q = m & 7;
    int n = base + nl;
    float4 a0 = {0,0,0,0}, a1 = {0,0,0,0};
    gather_half(row, esrc, (const uint4*)hin, n, g2, q, a0, a1);
    a0.x += __shfl_xor(a0.x, 8); a0.y += __shfl_xor(a0.y, 8);
    a0.z += __shfl_xor(a0.z, 8); a0.w += __shfl_xor(a0.w, 8);
    a1.x += __shfl_xor(a1.x, 8); a1.y += __shfl_xor(a1.y, 8);
    a1.z += __shfl_xor(a1.z, 8); a1.w += __shfl_xor(a1.w, 8);
    float s = dinv[n];
    float4 b0 = ((const float4*)bias)[2 * q];
    float4 b1 = ((const float4*)bias)[2 * q + 1];
    if (g2 == 0) {
        float4 r0, r1;
        r0.x = fmaxf(a0.x * s + b0.x, 0.f);
        r0.y = fmaxf(a0.y * s + b0.y, 0.f);
        r0.z = fmaxf(a0.z * s + b0.z, 0.f);
        r0.w = fmaxf(a0.w * s + b0.w, 0.f);
        r1.x = fmaxf(a1.x * s + b1.x, 0.f);
        r1.y = fmaxf(a1.y * s + b1.y, 0.f);
        r1.z = fmaxf(a1.z * s + b1.z, 0.f);
        r1.w = fmaxf(a1.w * s + b1.w, 0.f);
        *(float4*)&zf[nl * 68 + q * 8]     = r0;
        *(float4*)&zf[nl * 68 + q * 8 + 4] = r1;
    }
    __syncthreads();
    // pool: 4 groups x 4 nodes, 64 feats; batch sorted -> few boundary atomics
    int f = t & 63, grp = t >> 6;
    int n0 = grp * 4;
    int cur = bsh[n0];
    float acc = 0.f;
#pragma unroll
    for (int k2 = 0; k2 < 4; ++k2) {
        int bb = bsh[n0 + k2];
        if (bb != cur) { atomicAdd(&g[cur * D + f], acc); acc = 0.f; cur = bb; }
        acc += zf[(n0 + k2) * 68 + f];
    }
    atomicAdd(&g[cur * D + f], acc);
}

// ---------------- fused MLP ----------------
__global__ void k_mlp(const float* __restrict__ g, const float* __restrict__ W1,
                      const float* __restrict__ b1, const float* __restrict__ W2,
                      const float* __restrict__ b2, float* __restrict__ out) {
    __shared__ float red[FINAL_NEURON];
    int row = blockIdx.x;
    int j = threadIdx.x;
    float acc = 0.f;
#pragma unroll
    for (int k = 0; k < D; ++k) acc += g[row * D + k] * W1[k * FINAL_NEURON + j];
    acc = fmaxf(acc + b1[j], 0.f);
    red[j] = acc * W2[j];
    __syncthreads();
    for (int s = 64; s > 0; s >>= 1) {
        if (j < s) red[j] += red[j + s];
        __syncthreads();
    }
    if (j == 0) out[row] = red[0] + b2[0];
}

extern "C" void kernel_launch(void* const* d_in, const int* in_sizes, int n_in,
                              void* d_out, int out_size, void* d_ws, size_t ws_size,
                              hipStream_t stream) {
    const float* x     = (const float*)d_in[0];
    const int*   ei    = (const int*)d_in[1];
    const int*   src   = ei;
    const int*   dst   = ei + N_EDGES;
    const int*   batch = (const int*)d_in[2];
    WPtrs wp;
    wp.w[0] = (const float*)d_in[3];  wp.w[1] = (const float*)d_in[5];
    wp.w[2] = (const float*)d_in[7];  wp.w[3] = (const float*)d_in[9];
    wp.w[4] = (const float*)d_in[11];
    const float* b[5]  = {(const float*)d_in[4], (const float*)d_in[6], (const float*)d_in[8],
                          (const float*)d_in[10], (const float*)d_in[12]};
    const float* fc1W  = (const float*)d_in[13];
    const float* fc1b  = (const float*)d_in[14];
    const float* fc2W  = (const float*)d_in[15];
    const float* fc2b  = (const float*)d_in[16];
    float* out = (float*)d_out;

    __half*   yA   = (__half*)d_ws;                      // [N][64] fp16
    __half*   yB   = yA + (size_t)N_NODES * D;           // [N][64] fp16
    f16*      whiG = (f16*)(yB + (size_t)N_NODES * D);   // 5 * WELEM
    f16*      wloG = whiG + 5 * WELEM;                   // 5 * WELEM
    float*    g    = (float*)(wloG + 5 * WELEM);         // G*D
    float*    dinv = g + NUM_GRAPHS * D;                 // N
    int*      cnt  = (int*)(dinv + N_NODES);             // N
    int*      row  = cnt + N_NODES;                      // N+1
    int*      bsum = row + N_NODES + 1;                  // 256
    ushort_t* epos = (ushort_t*)(bsum + 256);            // E ushort
    ushort_t* esrc = epos + N_EDGES;                     // E ushort (+pad)

    // ---- CSR build + W prep (merged scan: 4 kernels) ----
    k_zero_prep<<<SCAN_NB + 5, 256, 0, stream>>>(cnt, wp, whiG, wloG);
    k_hist<<<NB_EDGE, 256, 0, stream>>>(dst, cnt, epos);
    k_blocksum<<<SCAN_NB, 256, 0, stream>>>(cnt, bsum, dinv, g);
    k_localscan<<<SCAN_NB, 256, 0, stream>>>(bsum, cnt, row);

    // ---- y1 = dinv*(x@W1) + CSR fill (one kernel, two block ranges) ----
    k_transform0<<<NB_GEMM + NB_EDGE, 256, 0, stream>>>(x, dinv, whiG, wloG, yA,
                                                        src, dst, row, epos, esrc);

    // ---- 4 fused GCN layers ----
    k_layer<<<NB_GEMM, 256, 0, stream>>>(row, esrc, yA, dinv, b[0],
                                         whiG + 1 * WELEM, wloG + 1 * WELEM, yB);
    k_layer<<<NB_GEMM, 256, 0, stream>>>(row, esrc, yB, dinv, b[1],
                                         whiG + 2 * WELEM, wloG + 2 * WELEM, yA);
    k_layer<<<NB_GEMM, 256, 0, stream>>>(row, esrc, yA, dinv, b[2],
                                         whiG + 3 * WELEM, wloG + 3 * WELEM, yB);
    k_layer<<<NB_GEMM, 256, 0, stream>>>(row, esrc, yB, dinv, b[3],
                                         whiG + 4 * WELEM, wloG + 4 * WELEM, yA);

    // ---- layer 5 + fused global_add_pool ----
    k_layer_pool<<<NB_GEMM, 256, 0, stream>>>(row, esrc, yA, dinv, b[4], batch, g);

    // ---- MLP ----
    k_mlp<<<NUM_GRAPHS, FINAL_NEURON, 0, stream>>>(g, fc1W, fc1b, fc2W, fc2b, out);
}

// Round 11
// 238.354 us; speedup vs baseline: 1.0922x; 1.0889x over previous
//
#include <hip/hip_runtime.h>
#include <hip/hip_fp16.h>

#define N_NODES 50000
#define N_EDGES 800000
#define D 64
#define NUM_GRAPHS 512
#define FINAL_NEURON 128
#define SCAN_NB ((N_NODES + 255) / 256)   // 196

#define BN 16                              // nodes per GEMM tile (50000/16 exact)
#define NB_GEMM (N_NODES / BN)             // 3125
#define NB_EDGE (N_EDGES / 256)            // 3125 exact
#define ZS 72                              // LDS stride (halves)
#define WS 72
#define WELEM (D * WS)                     // 4608 halves per prepared W image

typedef unsigned short ushort_t;
typedef _Float16 f16;
typedef __attribute__((ext_vector_type(4))) _Float16 f16x4;
typedef __attribute__((ext_vector_type(8))) _Float16 f16x8;
typedef __attribute__((ext_vector_type(4))) float f32x4;

struct WPtrs { const float* w[5]; };

__device__ __forceinline__ float2 h2f(unsigned v) {
    __half2 h = *reinterpret_cast<__half2*>(&v);
    return __half22float2(h);
}

__device__ __forceinline__ void acc_add8(float4& a0, float4& a1, uint4 u) {
    float2 p;
    p = h2f(u.x); a0.x += p.x; a0.y += p.y;
    p = h2f(u.y); a0.z += p.x; a0.w += p.y;
    p = h2f(u.z); a1.x += p.x; a1.y += p.y;
    p = h2f(u.w); a1.z += p.x; a1.w += p.y;
}

// ---------------- CSR build + W hi/lo prep (R5-verified) ----------------
__global__ void k_zero_prep(int* cnt, WPtrs wp, f16* __restrict__ whi, f16* __restrict__ wlo) {
    int b = blockIdx.x;
    if (b < SCAN_NB) {
        int i = b * 256 + threadIdx.x;
        if (i < N_NODES) cnt[i] = 0;
        return;
    }
    int l = b - SCAN_NB;                 // 0..4
    const float* W = wp.w[l];
    f16* hi = whi + l * WELEM;
    f16* lo = wlo + l * WELEM;
    for (int idx = threadIdx.x; idx < D * D; idx += 256) {
        int k = idx >> 6, j = idx & 63;
        float w = W[idx];
        f16 h = (f16)w;
        hi[j * WS + k] = h;
        lo[j * WS + k] = (f16)(w - (float)h);
    }
}

// hist: returning atomic + coalesced epos write (packed row-CSR rank)
__global__ void k_hist(const int* __restrict__ dst, int* cnt, ushort_t* __restrict__ epos) {
    int e = blockIdx.x * 256 + threadIdx.x;
    epos[e] = (ushort_t)atomicAdd(&cnt[dst[e]], 1);
}

__global__ void k_blocksum(const int* __restrict__ cnt, int* __restrict__ bsum,
                           float* __restrict__ dinv, float* __restrict__ g) {
    __shared__ int sdata[256];
    int t = threadIdx.x;
    int i = blockIdx.x * 256 + t;
    int v = (i < N_NODES) ? cnt[i] : 0;
    if (i < N_NODES) dinv[i] = rsqrtf((float)v + 1.0f);
    if (i < NUM_GRAPHS * D) g[i] = 0.f;
    sdata[t] = v;
    __syncthreads();
    for (int s = 128; s > 0; s >>= 1) {
        if (t < s) sdata[t] += sdata[t + s];
        __syncthreads();
    }
    if (t == 0) bsum[blockIdx.x] = sdata[0];
}

// merged scan: each block derives its own exclusive offset from bsum in LDS
// (redundant 256-wide scan, trivially parallel) then local-scans its cnt chunk.
__global__ void k_localscan(const int* __restrict__ bsum, const int* __restrict__ cnt,
                            int* __restrict__ row) {
    __shared__ int buf[256];
    int t = threadIdx.x;
    // pass 1: inclusive scan over the 196 block sums
    int bv = (t < SCAN_NB) ? bsum[t] : 0;
    buf[t] = bv;
    __syncthreads();
    for (int off = 1; off < 256; off <<= 1) {
        int a = (t >= off) ? buf[t - off] : 0;
        __syncthreads();
        buf[t] += a;
        __syncthreads();
    }
    int boff = buf[blockIdx.x] - bsum[blockIdx.x];   // exclusive prefix (uniform)
    __syncthreads();
    // pass 2: local scan of this block's cnt chunk
    int i = blockIdx.x * 256 + t;
    int v = (i < N_NODES) ? cnt[i] : 0;
    buf[t] = v;
    __syncthreads();
    for (int off = 1; off < 256; off <<= 1) {
        int a = (t >= off) ? buf[t - off] : 0;
        __syncthreads();
        buf[t] += a;
        __syncthreads();
    }
    if (i < N_NODES) row[i] = boff + buf[t] - v;
    if (i == 0) row[N_NODES] = N_EDGES;
}

// ---------------- gather: contiguous-half split, 8-wide rounds (verified) ----
__device__ __forceinline__ void gather_half(const int* __restrict__ row,
                                            const ushort_t* __restrict__ esrc,
                                            const uint4* __restrict__ hp,
                                            int n, int g, int q,
                                            float4& a0, float4& a1) {
    int e0 = row[n], e1 = row[n + 1];
    int len = e1 - e0;
    int h0 = (len + 1) >> 1;
    int e  = g ? (e0 + h0) : e0;
    int eg = g ? e1 : (e0 + h0);
    if (g) acc_add8(a0, a1, hp[(size_t)n * 8 + q]);   // self-loop (shorter half)
    int m = eg - e;
    int i0, i1, i2, i3, i4, i5, i6, i7;
    if (m >= 8) {
        i0 = esrc[e];     i1 = esrc[e + 1]; i2 = esrc[e + 2]; i3 = esrc[e + 3];
        i4 = esrc[e + 4]; i5 = esrc[e + 5]; i6 = esrc[e + 6]; i7 = esrc[e + 7];
        for (;;) {
            uint4 u0 = hp[(size_t)i0 * 8 + q], u1 = hp[(size_t)i1 * 8 + q];
            uint4 u2 = hp[(size_t)i2 * 8 + q], u3 = hp[(size_t)i3 * 8 + q];
            uint4 u4 = hp[(size_t)i4 * 8 + q], u5 = hp[(size_t)i5 * 8 + q];
            uint4 u6 = hp[(size_t)i6 * 8 + q], u7 = hp[(size_t)i7 * 8 + q];
            e += 8; m -= 8;
            i0 = esrc[e];     i1 = esrc[e + 1]; i2 = esrc[e + 2]; i3 = esrc[e + 3];
            i4 = esrc[e + 4]; i5 = esrc[e + 5]; i6 = esrc[e + 6]; i7 = esrc[e + 7];
            acc_add8(a0, a1, u0); acc_add8(a0, a1, u1);
            acc_add8(a0, a1, u2); acc_add8(a0, a1, u3);
            acc_add8(a0, a1, u4); acc_add8(a0, a1, u5);
            acc_add8(a0, a1, u6); acc_add8(a0, a1, u7);
            if (m < 8) break;
        }
        // i0..i7 hold the next 8 prefetched entries; first m are valid tail
    } else {
        if (m <= 0) return;
        i0 = esrc[e];     i1 = esrc[e + 1]; i2 = esrc[e + 2]; i3 = esrc[e + 3];
        i4 = esrc[e + 4]; i5 = esrc[e + 5]; i6 = esrc[e + 6]; i7 = esrc[e + 7];
    }
    if (m & 4) {
        uint4 u0 = hp[(size_t)i0 * 8 + q], u1 = hp[(size_t)i1 * 8 + q];
        uint4 u2 = hp[(size_t)i2 * 8 + q], u3 = hp[(size_t)i3 * 8 + q];
        acc_add8(a0, a1, u0); acc_add8(a0, a1, u1);
        acc_add8(a0, a1, u2); acc_add8(a0, a1, u3);
        i0 = i4; i1 = i5; i2 = i6; i3 = i7;
    }
    if (m & 2) {
        uint4 u0 = hp[(size_t)i0 * 8 + q], u1 = hp[(size_t)i1 * 8 + q];
        acc_add8(a0, a1, u0); acc_add8(a0, a1, u1);
        i0 = i2; i1 = i3;
    }
    if (m & 1) {
        uint4 u0 = hp[(size_t)i0 * 8 + q];
        acc_add8(a0, a1, u0);
    }
}

// ---------------- 16x64 @ 64x64 MFMA GEMM, W from global (verified) ----------
__device__ __forceinline__ void gemm_16x64_reg(f16* zsh,
                                               const f16* __restrict__ whi_g,
                                               const f16* __restrict__ wlo_g,
                                               const float* dinvsh, int t) {
    int w = t >> 6, l = t & 63;
    int cb = w * 16;
    int lr = l & 15, lg = l >> 4;
    const f16* bhp = &whi_g[(cb + lr) * WS + lg * 8];
    const f16* blp = &wlo_g[(cb + lr) * WS + lg * 8];
    f16x8 bh0 = *(const f16x8*)bhp;
    f16x8 bl0 = *(const f16x8*)blp;
    f16x8 bh1 = *(const f16x8*)(bhp + 32);
    f16x8 bl1 = *(const f16x8*)(blp + 32);
    f32x4 acc = {0.f, 0.f, 0.f, 0.f};
    f16x8 a0 = *(const f16x8*)&zsh[lr * ZS + lg * 8];
    f16x8 a1 = *(const f16x8*)&zsh[lr * ZS + 32 + lg * 8];
    acc = __builtin_amdgcn_mfma_f32_16x16x32_f16(a0, bh0, acc, 0, 0, 0);
    acc = __builtin_amdgcn_mfma_f32_16x16x32_f16(a0, bl0, acc, 0, 0, 0);
    acc = __builtin_amdgcn_mfma_f32_16x16x32_f16(a1, bh1, acc, 0, 0, 0);
    acc = __builtin_amdgcn_mfma_f32_16x16x32_f16(a1, bl1, acc, 0, 0, 0);
    __syncthreads();                 // all zsh reads done before overwrite
    // C/D layout: col = lane&15, row = (lane>>4)*4 + reg
#pragma unroll
    for (int r = 0; r < 4; ++r) {
        int rrow = lg * 4 + r;
        float s = dinvsh[rrow];
        zsh[rrow * ZS + cb + lr] = (f16)(acc[r] * s);
    }
}

// ---------------- transform0: y1 = dinv .* (x @ W1), fp16; + CSR edge fill ---
__global__ __launch_bounds__(256, 8)
void k_transform0(const float* __restrict__ x, const float* __restrict__ dinv,
                  const f16* __restrict__ whi_g, const f16* __restrict__ wlo_g,
                  __half* __restrict__ hout,
                  const int* __restrict__ src, const int* __restrict__ dst,
                  const int* __restrict__ row, const ushort_t* __restrict__ epos,
                  ushort_t* __restrict__ esrc) {
    int t = threadIdx.x;
    if (blockIdx.x >= NB_GEMM) {           // fill blocks (plain store: L2 absorbs
        int e = (blockIdx.x - NB_GEMM) * 256 + t;   // the 1.6MB scatter; nt hint
        esrc[row[dst[e]] + (int)epos[e]] = (ushort_t)src[e];  // cost +17us, R10)
        return;
    }
    __shared__ __attribute__((aligned(16))) f16 zsh[BN * ZS];
    __shared__ float dinvsh[BN];
    int base = blockIdx.x * BN;
    if (t < BN) dinvsh[t] = dinv[base + t];

    int nl = t >> 4, c4 = t & 15;
    float4 xv = ((const float4*)x)[(size_t)(base + nl) * 16 + c4];
    f16x4 zv = {(f16)xv.x, (f16)xv.y, (f16)xv.z, (f16)xv.w};
    *(f16x4*)&zsh[nl * ZS + c4 * 4] = zv;
    __syncthreads();
    gemm_16x64_reg(zsh, whi_g, wlo_g, dinvsh, t);
    __syncthreads();
    if (t < 128) {
        int n2 = t >> 3, q = t & 7;
        uint4 o = *(const uint4*)&zsh[n2 * ZS + q * 8];
        ((uint4*)hout)[(size_t)(base + n2) * 8 + q] = o;
    }
}

// ---------------- fused layer: gather + relu/bias + (z @ Wnext)*dinv ---------
__global__ __launch_bounds__(256, 7)
void k_layer(const int* __restrict__ row, const ushort_t* __restrict__ esrc,
             const __half* __restrict__ hin, const float* __restrict__ dinv,
             const float* __restrict__ bias,
             const f16* __restrict__ whi_g, const f16* __restrict__ wlo_g,
             __half* __restrict__ hout) {
    __shared__ __attribute__((aligned(16))) f16 zsh[BN * ZS];
    __shared__ float dinvsh[BN];
    int t = threadIdx.x;
    int base = blockIdx.x * BN;
    if (t < BN) dinvsh[t] = dinv[base + t];

    int nl = t >> 4, m = t & 15, g = m >> 3, q = m & 7;
    int n = base + nl;
    float4 a0 = {0,0,0,0}, a1 = {0,0,0,0};
    gather_half(row, esrc, (const uint4*)hin, n, g, q, a0, a1);
    // merge the two edge-half partials
    a0.x += __shfl_xor(a0.x, 8); a0.y += __shfl_xor(a0.y, 8);
    a0.z += __shfl_xor(a0.z, 8); a0.w += __shfl_xor(a0.w, 8);
    a1.x += __shfl_xor(a1.x, 8); a1.y += __shfl_xor(a1.y, 8);
    a1.z += __shfl_xor(a1.z, 8); a1.w += __shfl_xor(a1.w, 8);
    float s = dinv[n];
    float4 b0 = ((const float4*)bias)[2 * q];
    float4 b1 = ((const float4*)bias)[2 * q + 1];
    if (g == 0) {
        f16x8 zv;
        zv[0] = (f16)fmaxf(a0.x * s + b0.x, 0.f);
        zv[1] = (f16)fmaxf(a0.y * s + b0.y, 0.f);
        zv[2] = (f16)fmaxf(a0.z * s + b0.z, 0.f);
        zv[3] = (f16)fmaxf(a0.w * s + b0.w, 0.f);
        zv[4] = (f16)fmaxf(a1.x * s + b1.x, 0.f);
        zv[5] = (f16)fmaxf(a1.y * s + b1.y, 0.f);
        zv[6] = (f16)fmaxf(a1.z * s + b1.z, 0.f);
        zv[7] = (f16)fmaxf(a1.w * s + b1.w, 0.f);
        *(f16x8*)&zsh[nl * ZS + q * 8] = zv;
    }
    __syncthreads();
    gemm_16x64_reg(zsh, whi_g, wlo_g, dinvsh, t);
    __syncthreads();
    if (t < 128) {
        int n2 = t >> 3, q2 = t & 7;
        uint4 o = *(const uint4*)&zsh[n2 * ZS + q2 * 8];
        ((uint4*)hout)[(size_t)(base + n2) * 8 + q2] = o;
    }
}

// ---------------- final layer: gather + relu/bias + fused global_add_pool ----
__global__ __launch_bounds__(256, 7)
void k_layer_pool(const int* __restrict__ row, const ushort_t* __restrict__ esrc,
                  const __half* __restrict__ hin, const float* __restrict__ dinv,
                  const float* __restrict__ bias, const int* __restrict__ batch,
                  float* __restrict__ g) {
    __shared__ float zf[BN * 68];
    __shared__ int bsh[BN];
    int t = threadIdx.x;
    int base = blockIdx.x * BN;
    if (t < BN) bsh[t] = batch[base + t];

    int nl = t >> 4, m = t & 15, g2 = m >> 3, q = m & 7;
    int n = base + nl;
    float4 a0 = {0,0,0,0}, a1 = {0,0,0,0};
    gather_half(row, esrc, (const uint4*)hin, n, g2, q, a0, a1);
    a0.x += __shfl_xor(a0.x, 8); a0.y += __shfl_xor(a0.y, 8);
    a0.z += __shfl_xor(a0.z, 8); a0.w += __shfl_xor(a0.w, 8);
    a1.x += __shfl_xor(a1.x, 8); a1.y += __shfl_xor(a1.y, 8);
    a1.z += __shfl_xor(a1.z, 8); a1.w += __shfl_xor(a1.w, 8);
    float s = dinv[n];
    float4 b0 = ((const float4*)bias)[2 * q];
    float4 b1 = ((const float4*)bias)[2 * q + 1];
    if (g2 == 0) {
        float4 r0, r1;
        r0.x = fmaxf(a0.x * s + b0.x, 0.f);
        r0.y = fmaxf(a0.y * s + b0.y, 0.f);
        r0.z = fmaxf(a0.z * s + b0.z, 0.f);
        r0.w = fmaxf(a0.w * s + b0.w, 0.f);
        r1.x = fmaxf(a1.x * s + b1.x, 0.f);
        r1.y = fmaxf(a1.y * s + b1.y, 0.f);
        r1.z = fmaxf(a1.z * s + b1.z, 0.f);
        r1.w = fmaxf(a1.w * s + b1.w, 0.f);
        *(float4*)&zf[nl * 68 + q * 8]     = r0;
        *(float4*)&zf[nl * 68 + q * 8 + 4] = r1;
    }
    __syncthreads();
    // pool: 4 groups x 4 nodes, 64 feats; batch sorted -> few boundary atomics
    int f = t & 63, grp = t >> 6;
    int n0 = grp * 4;
    int cur = bsh[n0];
    float acc = 0.f;
#pragma unroll
    for (int k2 = 0; k2 < 4; ++k2) {
        int bb = bsh[n0 + k2];
        if (bb != cur) { atomicAdd(&g[cur * D + f], acc); acc = 0.f; cur = bb; }
        acc += zf[(n0 + k2) * 68 + f];
    }
    atomicAdd(&g[cur * D + f], acc);
}

// ---------------- fused MLP ----------------
__global__ void k_mlp(const float* __restrict__ g, const float* __restrict__ W1,
                      const float* __restrict__ b1, const float* __restrict__ W2,
                      const float* __restrict__ b2, float* __restrict__ out) {
    __shared__ float red[FINAL_NEURON];
    int row = blockIdx.x;
    int j = threadIdx.x;
    float acc = 0.f;
#pragma unroll
    for (int k = 0; k < D; ++k) acc += g[row * D + k] * W1[k * FINAL_NEURON + j];
    acc = fmaxf(acc + b1[j], 0.f);
    red[j] = acc * W2[j];
    __syncthreads();
    for (int s = 64; s > 0; s >>= 1) {
        if (j < s) red[j] += red[j + s];
        __syncthreads();
    }
    if (j == 0) out[row] = red[0] + b2[0];
}

extern "C" void kernel_launch(void* const* d_in, const int* in_sizes, int n_in,
                              void* d_out, int out_size, void* d_ws, size_t ws_size,
                              hipStream_t stream) {
    const float* x     = (const float*)d_in[0];
    const int*   ei    = (const int*)d_in[1];
    const int*   src   = ei;
    const int*   dst   = ei + N_EDGES;
    const int*   batch = (const int*)d_in[2];
    WPtrs wp;
    wp.w[0] = (const float*)d_in[3];  wp.w[1] = (const float*)d_in[5];
    wp.w[2] = (const float*)d_in[7];  wp.w[3] = (const float*)d_in[9];
    wp.w[4] = (const float*)d_in[11];
    const float* b[5]  = {(const float*)d_in[4], (const float*)d_in[6], (const float*)d_in[8],
                          (const float*)d_in[10], (const float*)d_in[12]};
    const float* fc1W  = (const float*)d_in[13];
    const float* fc1b  = (const float*)d_in[14];
    const float* fc2W  = (const float*)d_in[15];
    const float* fc2b  = (const float*)d_in[16];
    float* out = (float*)d_out;

    __half*   yA   = (__half*)d_ws;                      // [N][64] fp16
    __half*   yB   = yA + (size_t)N_NODES * D;           // [N][64] fp16
    f16*      whiG = (f16*)(yB + (size_t)N_NODES * D);   // 5 * WELEM
    f16*      wloG = whiG + 5 * WELEM;                   // 5 * WELEM
    float*    g    = (float*)(wloG + 5 * WELEM);         // G*D
    float*    dinv = g + NUM_GRAPHS * D;                 // N
    int*      cnt  = (int*)(dinv + N_NODES);             // N
    int*      row  = cnt + N_NODES;                      // N+1
    int*      bsum = row + N_NODES + 1;                  // 256
    ushort_t* epos = (ushort_t*)(bsum + 256);            // E ushort
    ushort_t* esrc = epos + N_EDGES;                     // E ushort (+pad)

    // ---- CSR build + W prep (merged scan: 4 kernels) ----
    k_zero_prep<<<SCAN_NB + 5, 256, 0, stream>>>(cnt, wp, whiG, wloG);
    k_hist<<<NB_EDGE, 256, 0, stream>>>(dst, cnt, epos);
    k_blocksum<<<SCAN_NB, 256, 0, stream>>>(cnt, bsum, dinv, g);
    k_localscan<<<SCAN_NB, 256, 0, stream>>>(bsum, cnt, row);

    // ---- y1 = dinv*(x@W1) + CSR fill (one kernel, two block ranges) ----
    k_transform0<<<NB_GEMM + NB_EDGE, 256, 0, stream>>>(x, dinv, whiG, wloG, yA,
                                                        src, dst, row, epos, esrc);

    // ---- 4 fused GCN layers ----
    k_layer<<<NB_GEMM, 256, 0, stream>>>(row, esrc, yA, dinv, b[0],
                                         whiG + 1 * WELEM, wloG + 1 * WELEM, yB);
    k_layer<<<NB_GEMM, 256, 0, stream>>>(row, esrc, yB, dinv, b[1],
                                         whiG + 2 * WELEM, wloG + 2 * WELEM, yA);
    k_layer<<<NB_GEMM, 256, 0, stream>>>(row, esrc, yA, dinv, b[2],
                                         whiG + 3 * WELEM, wloG + 3 * WELEM, yB);
    k_layer<<<NB_GEMM, 256, 0, stream>>>(row, esrc, yB, dinv, b[3],
                                         whiG + 4 * WELEM, wloG + 4 * WELEM, yA);

    // ---- layer 5 + fused global_add_pool ----
    k_layer_pool<<<NB_GEMM, 256, 0, stream>>>(row, esrc, yA, dinv, b[4], batch, g);

    // ---- MLP ----
    k_mlp<<<NUM_GRAPHS, FINAL_NEURON, 0, stream>>>(g, fc1W, fc1b, fc2W, fc2b, out);
}